// Round 1
// 86.406 us; speedup vs baseline: 1.0334x; 1.0334x over previous
//
#include <hip/hip_runtime.h>
#include <hip/hip_fp16.h>
#include <math.h>

// Problem constants (from reference)
#define NUM_TREES 256
#define DEPTH 6
#define TREE_DIM 2
#define INPUT_DIM 256
#define BATCH 2048
#define NLEAF 64                     // 2^DEPTH
#define NCOLS (NUM_TREES * DEPTH)    // 1536
#define KDIM INPUT_DIM

typedef _Float16 half8 __attribute__((ext_vector_type(8)));
typedef float floatx4 __attribute__((ext_vector_type(4)));
typedef float floatx2 __attribute__((ext_vector_type(2)));

// ---------------------------------------------------------------------------
// Kernel A (R7): fp32->fp16 convert of inputs + sparsemax, one wave per
// (tree,depth) column. selT is fp16 col-major (k contiguous, 8 padded
// cols/tree) = MFMA B-fragment order.
// R7 changes vs R6:
//  1. 16 binary bisection rounds -> 6 quaternary rounds (3 midpoints/round,
//     3 INDEPENDENT butterflies that pipeline; 2 bits/round) + 1 exact
//     simplex-projection finish: tau = (sum_{x>mid} x - 1)/k. Serial
//     shuffle-latency chain 17 -> 8 reduction rounds; tau now exact
//     (bracket 2^-12 -> support resolved), absmax should hold or improve.
//  2. Also emits per-column epilogue affine (sa, sb) for kernel B:
//     sd = clamp(sa*f + sb), sa = 0.5*exp(-logt), sb = 0.5 - sa*thr.
//     Removes 12 v_exp_f32 + ~24 VALU per thread from kernel B's epilogue.
// ---------------------------------------------------------------------------
__global__ __launch_bounds__(256) void sparsemax_bisect(
    const float* __restrict__ fsl,     // [256][1536] fp32
    const float* __restrict__ inputs,  // [2048][256] fp32
    const float* __restrict__ thr,     // [256][6]
    const float* __restrict__ logt,    // [256][6]
    _Float16* __restrict__ selT,       // [2048][256] fp16, col-major (pad 8/tree)
    _Float16* __restrict__ inH,        // [2048][256] fp16
    float2* __restrict__ ab)           // [1536] {sa, sb} per column
{
    const int tid = threadIdx.x;
    {
        const int gid = blockIdx.x * 256 + tid;
        if (gid < (BATCH * INPUT_DIM) / 8) {
            const float4 v0 = ((const float4*)inputs)[gid * 2];
            const float4 v1 = ((const float4*)inputs)[gid * 2 + 1];
            half8 h;
            h[0] = (_Float16)v0.x; h[1] = (_Float16)v0.y;
            h[2] = (_Float16)v0.z; h[3] = (_Float16)v0.w;
            h[4] = (_Float16)v1.x; h[5] = (_Float16)v1.y;
            h[6] = (_Float16)v1.z; h[7] = (_Float16)v1.w;
            *(half8*)(inH + gid * 8) = h;
        }
    }

    const int lane = tid & 63;
    const int wave = tid >> 6;
    const int col  = blockIdx.x * 4 + wave;      // 0..1535
    const int n = col / 6;
    const int d = col - n * 6;

    float x[4];
#pragma unroll
    for (int j = 0; j < 4; ++j)
        x[j] = fsl[(j * 64 + lane) * NCOLS + col];

    float mx = fmaxf(fmaxf(x[0], x[1]), fmaxf(x[2], x[3]));
#pragma unroll
    for (int off = 32; off > 0; off >>= 1)
        mx = fmaxf(mx, __shfl_xor(mx, off));

    // Quaternary search: S(m) = sum max(x - m, 0) is monotone decreasing;
    // invariant S(lo) >= 1 >= S(hi). 6 rounds -> bracket width 4^-6 = 2^-12.
    float lo = mx - 1.0f, hi = mx;
#pragma unroll
    for (int it = 0; it < 6; ++it) {
        const float w  = hi - lo;
        const float m1 = lo + 0.25f * w;
        const float m2 = lo + 0.50f * w;
        const float m3 = lo + 0.75f * w;
        float s1 = 0.f, s2 = 0.f, s3 = 0.f;
#pragma unroll
        for (int j = 0; j < 4; ++j) {
            s1 += fmaxf(x[j] - m1, 0.0f);
            s2 += fmaxf(x[j] - m2, 0.0f);
            s3 += fmaxf(x[j] - m3, 0.0f);
        }
        // 3 independent butterflies: same 6-deep latency as one, pipelined.
#pragma unroll
        for (int off = 32; off > 0; off >>= 1) {
            s1 += __shfl_xor(s1, off);
            s2 += __shfl_xor(s2, off);
            s3 += __shfl_xor(s3, off);
        }
        // s1 >= s2 >= s3 (monotone), all lanes uniform -> cndmask chain.
        lo = (s3 > 1.0f) ? m3 : (s2 > 1.0f) ? m2 : (s1 > 1.0f) ? m1 : lo;
        hi = (s1 <= 1.0f) ? m1 : (s2 <= 1.0f) ? m2 : (s3 <= 1.0f) ? m3 : hi;
    }

    // Exact projection finish: support(tau*) == {x > mid} (bracket 2^-12),
    // tau = (sum_{support} x - 1) / |support|. mid < hi <= mx -> |support|>=1.
    const float mid = 0.5f * (lo + hi);
    float ssum = 0.f, scnt = 0.f;
#pragma unroll
    for (int j = 0; j < 4; ++j) {
        const bool in = x[j] > mid;
        ssum += in ? x[j] : 0.0f;
        scnt += in ? 1.0f : 0.0f;
    }
#pragma unroll
    for (int off = 32; off > 0; off >>= 1) {
        ssum += __shfl_xor(ssum, off);
        scnt += __shfl_xor(scnt, off);
    }
    const float tau = (ssum - 1.0f) / scnt;

    _Float16* dst = selT + (n * 8 + d) * KDIM;
#pragma unroll
    for (int j = 0; j < 4; ++j)
        dst[j * 64 + lane] = (_Float16)fmaxf(x[j] - tau, 0.0f);

    // Per-column epilogue affine for kernel B.
    if (lane == 0) {
        const float sa = 0.5f * __expf(-logt[col]);
        const float sb = 0.5f - sa * thr[col];
        ab[col] = make_float2(sa, sb);
    }
}

// ---------------------------------------------------------------------------
// Kernel B: fp16 MFMA GEMM fused with sparsemoid -> leaf DP -> response.
// R7 changes vs R6 (same 64x64x64 tiling, 1024 blocks):
//  1. Epilogue affine hoisted to kernel A (abS in LDS): sd = clamp(sa*f+sb),
//     drops 12 v_exp_f32 (quarter-rate) + thr/logt loads per thread.
//  2. Response tile staged PRE-PAIRED as float4 {r0[c], r0[c+32], r1[c],
//     r1[c+32]}: contraction does 32 broadcast ds_read_b128 instead of
//     128 ds_read_b32 per pair.
//  3. Contraction on 2-wide ext-vectors -> v_pk_fma_f32 candidates
//     (64 packed vs 128 scalar FMA; worst case scalarizes, no regression).
// ---------------------------------------------------------------------------
#define BM 64
#define BN 64
#define BK 64
#define AP 72    // padded halfs per A row (144 B): even 8-group spread on b128
#define BP 72
#define FVS 67   // odd stride: C-writes <=2-way, epilogue b32 reads 2-way
#define OSP 36   // outS stride (floats): float4-aligned, even 8-group spread

__global__ __launch_bounds__(256, 4) void odt_mfma_kernel(
    const _Float16* __restrict__ inH,   // [2048][256] fp16
    const _Float16* __restrict__ selT,  // [2048][256] fp16 col-major
    const float2* __restrict__ ab,      // [1536] {sa, sb}
    const float* __restrict__ resp,     // [256][2][64]
    float* __restrict__ out)            // [2048][512]
{
    __shared__ union {
        struct {
            _Float16 A[BM][AP];   // 9 KB
            _Float16 B[BN][BP];   // 9 KB
        } s;
        float fv[BM][FVS];        // 16.75 KB
    } u;
    __shared__ float4 respP[8][32];               // 4 KB, pre-paired
    __shared__ float2 abS[48];                    // 384 B
    __shared__ float outS[BM][OSP];               // 9 KB

    const int tid = threadIdx.x;
    const int b0 = blockIdx.x * BM;
    const int treeBase = blockIdx.y * 8;
    const int colBase  = blockIdx.y * BN;

    // Stage response tile pre-paired: respP[t][c2] = {r0[c2], r0[c2+32],
    // r1[c2], r1[c2+32]}. 4 coalesced stride-32 loads per 32-thread group.
    {
        const int tr = tid >> 5, c2 = tid & 31;
        const float* rb = resp + (treeBase + tr) * (TREE_DIM * NLEAF);
        respP[tr][c2] = make_float4(rb[c2], rb[32 + c2], rb[64 + c2], rb[96 + c2]);
        if (tid < 48) abS[tid] = ab[treeBase * DEPTH + tid];
    }

    const int lane = tid & 63;
    const int w    = tid >> 6;
    const int wm   = w >> 1, wn = w & 1;        // 2x2 wave grid, 32x32 tiles
    const int l16  = lane & 15, quad = lane >> 4;

    floatx4 acc[2][2];
#pragma unroll
    for (int mt = 0; mt < 2; ++mt)
#pragma unroll
        for (int nt = 0; nt < 2; ++nt)
            acc[mt][nt] = (floatx4){0.f, 0.f, 0.f, 0.f};

    // Staging roles: 64 rows/cols x 4 segments of 16 halfs (32 B/thread each).
    const int srow = tid >> 2, sseg = tid & 3;
    const _Float16* aBase = inH  + (b0 + srow) * KDIM + sseg * 16;
    const _Float16* bBase = selT + (colBase + srow) * KDIM + sseg * 16;

    // Prefetch K-step 0 into registers.
    half8 pa0 = *(const half8*)(aBase);
    half8 pa1 = *(const half8*)(aBase + 8);
    half8 pb0 = *(const half8*)(bBase);
    half8 pb1 = *(const half8*)(bBase + 8);

#pragma unroll
    for (int k0 = 0; k0 < KDIM; k0 += BK) {
        __syncthreads();
        // Stage prefetched registers into LDS.
        *(half8*)&u.s.A[srow][sseg * 16 + 0] = pa0;
        *(half8*)&u.s.A[srow][sseg * 16 + 8] = pa1;
        *(half8*)&u.s.B[srow][sseg * 16 + 0] = pb0;
        *(half8*)&u.s.B[srow][sseg * 16 + 8] = pb1;
        // Issue next K-step's loads now; latency hides under the MFMA phase.
        if (k0 + BK < KDIM) {
            pa0 = *(const half8*)(aBase + k0 + BK);
            pa1 = *(const half8*)(aBase + k0 + BK + 8);
            pb0 = *(const half8*)(bBase + k0 + BK);
            pb1 = *(const half8*)(bBase + k0 + BK + 8);
        }
        __syncthreads();

#pragma unroll
        for (int h = 0; h < 2; ++h) {
            const half8 bf0 = *(const half8*)&u.s.B[wn * 32 + l16][quad * 8 + h * 32];
            const half8 bf1 = *(const half8*)&u.s.B[wn * 32 + 16 + l16][quad * 8 + h * 32];
            const half8 af0 = *(const half8*)&u.s.A[wm * 32 + l16][quad * 8 + h * 32];
            const half8 af1 = *(const half8*)&u.s.A[wm * 32 + 16 + l16][quad * 8 + h * 32];
            acc[0][0] = __builtin_amdgcn_mfma_f32_16x16x32_f16(af0, bf0, acc[0][0], 0, 0, 0);
            acc[0][1] = __builtin_amdgcn_mfma_f32_16x16x32_f16(af0, bf1, acc[0][1], 0, 0, 0);
            acc[1][0] = __builtin_amdgcn_mfma_f32_16x16x32_f16(af1, bf0, acc[1][0], 0, 0, 0);
            acc[1][1] = __builtin_amdgcn_mfma_f32_16x16x32_f16(af1, bf1, acc[1][1], 0, 0, 0);
        }
    }

    __syncthreads();   // all A/B ds_reads retired before union overwrite

    // C/D layout (m89-verified): col = lane&15, row = quad*4 + reg.
#pragma unroll
    for (int mt = 0; mt < 2; ++mt)
#pragma unroll
        for (int nt = 0; nt < 2; ++nt)
#pragma unroll
            for (int r = 0; r < 4; ++r)
                u.fv[wm * 32 + mt * 16 + quad * 4 + r][wn * 32 + nt * 16 + l16] = acc[mt][nt][r];
    __syncthreads();

    // Epilogue: 512 (row, tree) pairs, 2 per thread; tree index wave-uniform.
#pragma unroll
    for (int p = 0; p < 2; ++p) {
        const int idx = tid + 256 * p;
        const int row = idx & 63;
        const int tl  = idx >> 6;           // 0..7, wave-uniform
        const float* f = &u.fv[row][tl * 8];
        const float2* abt = &abS[tl * DEPTH];

        float sd[DEPTH];
#pragma unroll
        for (int d = 0; d < DEPTH; ++d)
            sd[d] = fminf(fmaxf(fmaf(f[d], abt[d].x, abt[d].y), 0.0f), 1.0f);

        // DP over depths 0..4 (32 leaves); depth-5 factor folds into the
        // contraction. Leaf bit d == 1 -> factor (1 - sd[d]).
        float wv[NLEAF / 2];
        wv[0] = 1.0f;
#pragma unroll
        for (int d = 0; d < 5; ++d) {
            const int sz = 1 << d;
#pragma unroll
            for (int c2 = 0; c2 < 16; ++c2) {
                if (c2 < sz) {
                    const float t = wv[c2];
                    wv[c2]      = t * sd[d];
                    wv[c2 + sz] = t * (1.0f - sd[d]);
                }
            }
        }
        // Contraction: 32 broadcast ds_read_b128 + packed 2-wide FMA.
        const float4* rp = &respP[tl][0];
        floatx2 A0 = (floatx2){0.f, 0.f};   // {a0, c0}  (tree_dim 0, lo/hi)
        floatx2 A1 = (floatx2){0.f, 0.f};   // {a1, c1}  (tree_dim 1, lo/hi)
#pragma unroll
        for (int c2 = 0; c2 < 32; ++c2) {
            const float4 rr = rp[c2];
            const floatx2 w2 = (floatx2){wv[c2], wv[c2]};
            A0 = w2 * (floatx2){rr.x, rr.y} + A0;
            A1 = w2 * (floatx2){rr.z, rr.w} + A1;
        }
        const float s5 = sd[5], s5b = 1.0f - sd[5];
        float2 o;
        o.x = s5 * A0[0] + s5b * A0[1];
        o.y = s5 * A1[0] + s5b * A1[1];
        *(float2*)&outS[row][tl * 2] = o;   // LDS stage (8-B aligned)
    }
    __syncthreads();

    // Coalesced out write: block footprint = 64 rows x 16 consecutive floats.
    // Thread t -> row t>>2, float4 segment t&3: 16 lines per wave-store.
    {
        const int wrow = tid >> 2, wc = tid & 3;
        const float4 v = *(const float4*)&outS[wrow][wc * 4];
        *(float4*)(out + (b0 + wrow) * (NUM_TREES * TREE_DIM) + treeBase * 2 + wc * 4) = v;
    }
}

// ---------------------------------------------------------------------------
extern "C" void kernel_launch(void* const* d_in, const int* in_sizes, int n_in,
                              void* d_out, int out_size, void* d_ws, size_t ws_size,
                              hipStream_t stream) {
    const float* inputs = (const float*)d_in[0];  // [2048][256]
    const float* fsl    = (const float*)d_in[1];  // [256][256][6]
    const float* thr    = (const float*)d_in[2];  // [256][6]
    const float* logt   = (const float*)d_in[3];  // [256][6]
    const float* resp   = (const float*)d_in[4];  // [256][2][64]
    float* out = (float*)d_out;                   // [2048][512]
    _Float16* selT = (_Float16*)d_ws;                          // 1 MB
    _Float16* inH  = (_Float16*)((char*)d_ws + (1 << 20));     // 1 MB
    float2*   ab   = (float2*)((char*)d_ws + (2 << 20));       // 12 KB

    hipLaunchKernelGGL(sparsemax_bisect, dim3(NCOLS / 4), dim3(256), 0, stream,
                       fsl, inputs, thr, logt, selT, inH, ab);
    hipLaunchKernelGGL(odt_mfma_kernel, dim3(BATCH / BM, NUM_TREES / 8), dim3(256),
                       0, stream, inH, selT, ab, resp, out);
}